// Round 8
// baseline (426.999 us; speedup 1.0000x reference)
//
#include <hip/hip_runtime.h>
#include <hip/hip_cooperative_groups.h>

namespace cg = cooperative_groups;

#define DIM 256
#define KCAT 512
#define NB 256
#define NT 256

typedef unsigned short u16;
typedef unsigned int u32;
typedef __bf16 bf16x8 __attribute__((ext_vector_type(8)));
typedef float f32x4 __attribute__((ext_vector_type(4)));

__device__ inline float bf2f(u16 u){ union{u32 i; float f;} v; v.i=((u32)u)<<16; return v.f; }
__device__ inline u16 f2bf(float f){
  union{float f; u32 i;} v; v.f=f;
  u32 i=v.i;
  return (u16)((i + 0x7FFFu + ((i>>16)&1u)) >> 16);  // RNE
}
__device__ inline ushort4 cvt4(float4 v){
  ushort4 r; r.x=f2bf(v.x); r.y=f2bf(v.y); r.z=f2bf(v.z); r.w=f2bf(v.w); return r;
}

// ================= fused cooperative kernel (256 blocks x 256 thr) =================
__global__ __launch_bounds__(NT, 2) void k_fused(
    const float* __restrict__ x, const int* __restrict__ src, const int* __restrict__ dst,
    const float* __restrict__ Wl, const float* __restrict__ Wr, const float* __restrict__ br,
    float* __restrict__ out,
    int* __restrict__ counts, int* __restrict__ offsets, int* __restrict__ cursor,
    int* __restrict__ sorted, int* __restrict__ blocksum, int* __restrict__ blockpref,
    u16* __restrict__ xb, u16* __restrict__ aggr, u16* __restrict__ Wcat,
    int n_nodes, int E, int nX4, int nW4, int Mtiles)
{
  cg::grid_group grid = cg::this_grid();
  __shared__ int sm[16];
  int t = threadIdx.x, b = blockIdx.x;
  int g = b*NT + t;
  const int G = NB*NT;               // 65536
  int lane = t & 63, wid = t >> 6;

  // ---- A: zero counts + W->bf16 + x->bf16 ----
  for(int i=g; i<n_nodes; i+=G) counts[i] = 0;
  for(int i=g; i<2*nW4; i+=G){
    int sel = (i >= nW4);
    int ii  = sel ? i - nW4 : i;
    float4 v = sel ? ((const float4*)Wr)[ii] : ((const float4*)Wl)[ii];
    int col = ii >> 6, k4 = ii & 63;
    ((ushort4*)Wcat)[col*128 + sel*64 + k4] = cvt4(v);
  }
  for(int i=g; i<nX4; i+=G) ((ushort4*)xb)[i] = cvt4(((const float4*)x)[i]);
  grid.sync();

  // ---- B: in-degree histogram ----
  int E4 = E >> 2;
  for(int e=g; e<E4; e+=G){
    int4 d = ((const int4*)dst)[e];
    atomicAdd(counts + d.x, 1);
    atomicAdd(counts + d.y, 1);
    atomicAdd(counts + d.z, 1);
    atomicAdd(counts + d.w, 1);
  }
  if (g == 0) for(int e2 = E4*4; e2 < E; e2++) atomicAdd(counts + dst[e2], 1);
  grid.sync();

  // ---- C: two-level exclusive scan (n_nodes <= G, one elem/thread) ----
  int nblk = (n_nodes + NT - 1) / NT;          // 79
  int myv = (g < n_nodes) ? counts[g] : 0;
  int sc = myv;
  #pragma unroll
  for(int off=1; off<64; off<<=1){ int v = __shfl_up(sc, off, 64); if(lane >= off) sc += v; }
  if (lane == 63) sm[wid] = sc;
  __syncthreads();
  if (t == 0){ int run=0; for(int w=0; w<4; w++){ int v=sm[w]; sm[w]=run; run+=v; } sm[4]=run; }
  __syncthreads();
  int myprefix = sm[wid] + (sc - myv);
  if (t == 0 && b < nblk) blocksum[b] = sm[4];
  grid.sync();

  // block 0 scans the 79 block sums
  int v2 = 0;
  if (b == 0 && t < nblk) v2 = blocksum[t];
  int s2 = v2;
  #pragma unroll
  for(int off=1; off<64; off<<=1){ int u = __shfl_up(s2, off, 64); if(lane >= off) s2 += u; }
  if (b == 0 && t == 63) sm[8] = s2;
  __syncthreads();
  if (b == 0){
    int pref = s2 - v2;
    if (wid == 1) pref += sm[8];
    if (t < nblk) blockpref[t] = pref;
    if (t == 127) offsets[n_nodes] = sm[8] + s2;
  }
  grid.sync();

  if (g < n_nodes){
    int off = blockpref[b] + myprefix;
    offsets[g] = off;
    cursor[g]  = off;
  }
  grid.sync();

  // ---- D: scatter into CSR order ----
  for(int e=g; e<E4; e+=G){
    int4 s = ((const int4*)src)[e];
    int4 d = ((const int4*)dst)[e];
    sorted[atomicAdd(cursor + d.x, 1)] = s.x;
    sorted[atomicAdd(cursor + d.y, 1)] = s.y;
    sorted[atomicAdd(cursor + d.z, 1)] = s.z;
    sorted[atomicAdd(cursor + d.w, 1)] = s.w;
  }
  if (g == 0) for(int e2 = E4*4; e2 < E; e2++)
    sorted[atomicAdd(cursor + dst[e2], 1)] = src[e2];
  grid.sync();

  // ---- E: per-node mean (one wave per node, grid-strided) ----
  {
    const int NW = NB*4;
    const u16* xc = xb + lane*4;
    for(int node = b*4 + wid; node < n_nodes; node += NW){
      int b0 = offsets[node], b1 = offsets[node+1];
      float s0=0.f, s1=0.f, s2f=0.f, s3=0.f;
      int i = b0;
      for(; i+8 <= b1; i+=8){
        int idx[8];
        #pragma unroll
        for(int u=0;u<8;u++) idx[u] = sorted[i+u];
        ushort4 vv[8];
        #pragma unroll
        for(int u=0;u<8;u++) vv[u] = *(const ushort4*)(xc + (size_t)idx[u]*DIM);
        #pragma unroll
        for(int u=0;u<8;u++){
          s0 += bf2f(vv[u].x); s1 += bf2f(vv[u].y); s2f += bf2f(vv[u].z); s3 += bf2f(vv[u].w);
        }
      }
      for(; i < b1; i++){
        int sn = sorted[i];
        ushort4 vv = *(const ushort4*)(xc + (size_t)sn*DIM);
        s0 += bf2f(vv.x); s1 += bf2f(vv.y); s2f += bf2f(vv.z); s3 += bf2f(vv.w);
      }
      int deg = b1 - b0;
      float inv = 1.0f / (float)(deg > 1 ? deg : 1);
      ushort4 o;
      o.x = f2bf(s0*inv); o.y = f2bf(s1*inv); o.z = f2bf(s2f*inv); o.w = f2bf(s3*inv);
      *(ushort4*)(aggr + (size_t)node*DIM + lane*4) = o;
    }
  }
  grid.sync();

  // ---- F: GEMM over 500 virtual blocks, grid-strided ----
  int gemm_vb = ((Mtiles + 4)/5) * 2;          // 500
  int quad = lane >> 4, l16 = lane & 15;
  for(int vb = b; vb < gemm_vb; vb += NB){
    int half = vb & 1;
    int mb   = vb >> 1;
    int colbase = half*128 + wid*32;

    const u16* wbase = Wcat + (size_t)(colbase + l16)*KCAT + quad*8;
    bf16x8 B[2][16];
    #pragma unroll
    for(int ct=0; ct<2; ct++)
      #pragma unroll
      for(int kt=0; kt<16; kt++)
        B[ct][kt] = *(const bf16x8*)(wbase + (size_t)ct*16*KCAT + kt*32);

    int col0 = colbase + l16, col1 = col0 + 16;
    float bi0 = br[col0], bi1 = br[col1];

    #pragma unroll
    for(int tt=0; tt<5; tt++){
      int mt = mb*5 + tt;
      if (mt >= Mtiles) break;
      const u16* arowA = aggr + (size_t)(mt*16 + l16)*DIM + quad*8;
      const u16* arowX = xb   + (size_t)(mt*16 + l16)*DIM + quad*8;
      f32x4 acc0 = {0.f,0.f,0.f,0.f}, acc1 = {0.f,0.f,0.f,0.f};
      #pragma unroll
      for(int kt=0; kt<8; kt++){
        bf16x8 a = *(const bf16x8*)(arowA + kt*32);
        acc0 = __builtin_amdgcn_mfma_f32_16x16x32_bf16(a, B[0][kt], acc0, 0, 0, 0);
        acc1 = __builtin_amdgcn_mfma_f32_16x16x32_bf16(a, B[1][kt], acc1, 0, 0, 0);
      }
      #pragma unroll
      for(int kt=0; kt<8; kt++){
        bf16x8 a = *(const bf16x8*)(arowX + kt*32);
        acc0 = __builtin_amdgcn_mfma_f32_16x16x32_bf16(a, B[0][kt+8], acc0, 0, 0, 0);
        acc1 = __builtin_amdgcn_mfma_f32_16x16x32_bf16(a, B[1][kt+8], acc1, 0, 0, 0);
      }
      size_t base = (size_t)(mt*16 + quad*4)*DIM;
      #pragma unroll
      for(int r=0;r<4;r++){
        out[base + (size_t)r*DIM + col0] = acc0[r] + bi0;
        out[base + (size_t)r*DIM + col1] = acc1[r] + bi1;
      }
    }
  }
}

// ================= fallback pipeline (round-6, known good) =================
__global__ void k_zero(int* __restrict__ p, int n){
  int i = blockIdx.x*blockDim.x + threadIdx.x;
  if(i<n) p[i]=0;
}

__global__ __launch_bounds__(256) void k_hist_cvtw(const int* __restrict__ dst, int E,
    int* __restrict__ counts, const float* __restrict__ Wl, const float* __restrict__ Wr,
    u16* __restrict__ Wcat, int nW4){
  int E4 = E >> 2;
  int hb = (E4 + 255) >> 8;
  int b = blockIdx.x, t = threadIdx.x;
  if (b < hb){
    int e = b*256 + t;
    if(e < E4){
      int4 d = ((const int4*)dst)[e];
      atomicAdd(counts + d.x, 1);
      atomicAdd(counts + d.y, 1);
      atomicAdd(counts + d.z, 1);
      atomicAdd(counts + d.w, 1);
    }
    if (b==0 && t==0){
      for(int e2 = E4*4; e2 < E; e2++) atomicAdd(counts + dst[e2], 1);
    }
  } else {
    int i = (b - hb)*256 + t;
    if (i < 2*nW4){
      int sel = (i >= nW4);
      int ii = sel ? i - nW4 : i;
      float4 v = sel ? ((const float4*)Wr)[ii] : ((const float4*)Wl)[ii];
      int col = ii >> 6, k4 = ii & 63;
      ((ushort4*)Wcat)[col*128 + sel*64 + k4] = cvt4(v);
    }
  }
}

__global__ __launch_bounds__(1024) void k_scan(const int* __restrict__ counts, int n,
                                               int* __restrict__ offsets, int* __restrict__ cursor){
  __shared__ int wsum[16];
  int t = threadIdx.x;
  int s0 = t*20;
  int4 c[5];
  int s = 0;
  #pragma unroll
  for(int u=0; u<5; u++){
    int i = s0 + 4*u;
    int4 cv = {0,0,0,0};
    if (i + 3 < n){
      cv = *(const int4*)(counts + i);
    } else {
      if (i   < n) cv.x = counts[i];
      if (i+1 < n) cv.y = counts[i+1];
      if (i+2 < n) cv.z = counts[i+2];
      if (i+3 < n) cv.w = counts[i+3];
    }
    c[u] = cv;
    s += cv.x + cv.y + cv.z + cv.w;
  }
  int lane = t & 63, wid = t >> 6;
  int sc = s;
  #pragma unroll
  for(int off=1; off<64; off<<=1){
    int v = __shfl_up(sc, off, 64);
    if (lane >= off) sc += v;
  }
  if (lane == 63) wsum[wid] = sc;
  __syncthreads();
  if (t == 0){
    int run = 0;
    #pragma unroll
    for(int w=0; w<16; w++){ int v = wsum[w]; wsum[w] = run; run += v; }
  }
  __syncthreads();
  int run = wsum[wid] + (sc - s);
  #pragma unroll
  for(int u=0; u<5; u++){
    int i = s0 + 4*u;
    int4 o;
    o.x = run; run += c[u].x;
    o.y = run; run += c[u].y;
    o.z = run; run += c[u].z;
    o.w = run; run += c[u].w;
    if (i + 3 < n){
      *(int4*)(offsets + i) = o;
      *(int4*)(cursor  + i) = o;
    } else {
      if (i   < n){ offsets[i]   = o.x; cursor[i]   = o.x; }
      if (i+1 < n){ offsets[i+1] = o.y; cursor[i+1] = o.y; }
      if (i+2 < n){ offsets[i+2] = o.z; cursor[i+2] = o.z; }
      if (i+3 < n){ offsets[i+3] = o.w; cursor[i+3] = o.w; }
    }
  }
  if (t == 1023) offsets[n] = wsum[15] + sc;
}

__global__ __launch_bounds__(256) void k_scatter_cvtx(const int* __restrict__ src,
    const int* __restrict__ dst, int E, int* __restrict__ cursor, int* __restrict__ sorted_src,
    const float* __restrict__ x, u16* __restrict__ xb, int nX4){
  int E4 = E >> 2;
  int sb = (E4 + 255) >> 8;
  int b = blockIdx.x, t = threadIdx.x;
  if (b < sb){
    int e = b*256 + t;
    if(e < E4){
      int4 s = ((const int4*)src)[e];
      int4 d = ((const int4*)dst)[e];
      sorted_src[atomicAdd(cursor + d.x, 1)] = s.x;
      sorted_src[atomicAdd(cursor + d.y, 1)] = s.y;
      sorted_src[atomicAdd(cursor + d.z, 1)] = s.z;
      sorted_src[atomicAdd(cursor + d.w, 1)] = s.w;
    }
    if (b==0 && t==0){
      for(int e2 = E4*4; e2 < E; e2++)
        sorted_src[atomicAdd(cursor + dst[e2], 1)] = src[e2];
    }
  } else {
    int i = (b - sb)*256 + t;
    if (i < nX4) ((ushort4*)xb)[i] = cvt4(((const float4*)x)[i]);
  }
}

__global__ __launch_bounds__(256) void k_aggr(const u16* __restrict__ xb,
    const int* __restrict__ offsets, const int* __restrict__ sorted_src,
    u16* __restrict__ aggr, int n_nodes){
  int wave = threadIdx.x >> 6, lane = threadIdx.x & 63;
  int node = blockIdx.x*4 + wave;
  if(node >= n_nodes) return;
  int b0 = offsets[node], b1 = offsets[node+1];
  const u16* xc = xb + lane*4;
  float s0=0.f, s1=0.f, s2=0.f, s3=0.f;
  int i = b0;
  for(; i+8 <= b1; i+=8){
    int idx[8];
    #pragma unroll
    for(int u=0;u<8;u++) idx[u] = sorted_src[i+u];
    ushort4 v[8];
    #pragma unroll
    for(int u=0;u<8;u++) v[u] = *(const ushort4*)(xc + (size_t)idx[u]*DIM);
    #pragma unroll
    for(int u=0;u<8;u++){
      s0 += bf2f(v[u].x); s1 += bf2f(v[u].y); s2 += bf2f(v[u].z); s3 += bf2f(v[u].w);
    }
  }
  for(; i < b1; i++){
    int sn = sorted_src[i];
    ushort4 v = *(const ushort4*)(xc + (size_t)sn*DIM);
    s0 += bf2f(v.x); s1 += bf2f(v.y); s2 += bf2f(v.z); s3 += bf2f(v.w);
  }
  int deg = b1 - b0;
  float inv = 1.0f / (float)(deg > 1 ? deg : 1);
  ushort4 o;
  o.x = f2bf(s0*inv); o.y = f2bf(s1*inv); o.z = f2bf(s2*inv); o.w = f2bf(s3*inv);
  *(ushort4*)(aggr + (size_t)node*DIM + lane*4) = o;
}

__global__ __launch_bounds__(256, 2) void k_gemm(const u16* __restrict__ aggr,
    const u16* __restrict__ xb, const u16* __restrict__ Wcat, const float* __restrict__ br,
    float* __restrict__ out, int Mtiles){
  int wave = threadIdx.x >> 6, lane = threadIdx.x & 63;
  int quad = lane >> 4, l16 = lane & 15;
  int half = blockIdx.x & 1;
  int mb   = blockIdx.x >> 1;
  int colbase = half*128 + wave*32;

  const u16* wbase = Wcat + (size_t)(colbase + l16)*KCAT + quad*8;
  bf16x8 B[2][16];
  #pragma unroll
  for(int ct=0; ct<2; ct++)
    #pragma unroll
    for(int kt=0; kt<16; kt++)
      B[ct][kt] = *(const bf16x8*)(wbase + (size_t)ct*16*KCAT + kt*32);

  int col0 = colbase + l16, col1 = col0 + 16;
  float bi0 = br[col0], bi1 = br[col1];

  #pragma unroll
  for(int tt=0; tt<5; tt++){
    int mt = mb*5 + tt;
    if (mt >= Mtiles) break;
    const u16* arowA = aggr + (size_t)(mt*16 + l16)*DIM + quad*8;
    const u16* arowX = xb   + (size_t)(mt*16 + l16)*DIM + quad*8;
    f32x4 acc0 = {0.f,0.f,0.f,0.f}, acc1 = {0.f,0.f,0.f,0.f};
    #pragma unroll
    for(int kt=0; kt<8; kt++){
      bf16x8 a = *(const bf16x8*)(arowA + kt*32);
      acc0 = __builtin_amdgcn_mfma_f32_16x16x32_bf16(a, B[0][kt], acc0, 0, 0, 0);
      acc1 = __builtin_amdgcn_mfma_f32_16x16x32_bf16(a, B[1][kt], acc1, 0, 0, 0);
    }
    #pragma unroll
    for(int kt=0; kt<8; kt++){
      bf16x8 a = *(const bf16x8*)(arowX + kt*32);
      acc0 = __builtin_amdgcn_mfma_f32_16x16x32_bf16(a, B[0][kt+8], acc0, 0, 0, 0);
      acc1 = __builtin_amdgcn_mfma_f32_16x16x32_bf16(a, B[1][kt+8], acc1, 0, 0, 0);
    }
    size_t base = (size_t)(mt*16 + quad*4)*DIM;
    #pragma unroll
    for(int r=0;r<4;r++){
      out[base + (size_t)r*DIM + col0] = acc0[r] + bi0;
      out[base + (size_t)r*DIM + col1] = acc1[r] + bi1;
    }
  }
}

extern "C" void kernel_launch(void* const* d_in, const int* in_sizes, int n_in,
                              void* d_out, int out_size, void* d_ws, size_t ws_size,
                              hipStream_t stream){
  const float* x  = (const float*)d_in[0];
  const int*   ei = (const int*)d_in[1];
  const float* Wl = (const float*)d_in[2];
  const float* Wr = (const float*)d_in[3];
  const float* br = (const float*)d_in[4];
  float* out = (float*)d_out;
  int n_nodes = in_sizes[0] / DIM;   // 20000
  int E = in_sizes[1] / 2;           // 320000
  const int* src = ei;
  const int* dst = ei + E;

  int* counts    = (int*)d_ws;                   // [n]
  int* offsets   = counts + n_nodes;             // [n+1] (padded to n+8)
  int* cursor    = offsets + (n_nodes + 8);      // [n]
  int* blocksum  = cursor + n_nodes;             // [128]
  int* blockpref = blocksum + 128;               // [128]
  int* sorted    = blockpref + 128;              // [E]
  u16* xb        = (u16*)(sorted + E);           // [n*DIM] bf16
  u16* aggr      = xb + (size_t)n_nodes*DIM;     // [n*DIM] bf16
  u16* Wcat      = aggr + (size_t)n_nodes*DIM;   // [256*512] bf16

  int nX4 = n_nodes*DIM/4, nW4 = DIM*DIM/4;
  int Mtiles = n_nodes >> 4;                     // 1250

  void* args[] = {
    (void*)&x, (void*)&src, (void*)&dst, (void*)&Wl, (void*)&Wr, (void*)&br,
    (void*)&out,
    (void*)&counts, (void*)&offsets, (void*)&cursor, (void*)&sorted,
    (void*)&blocksum, (void*)&blockpref,
    (void*)&xb, (void*)&aggr, (void*)&Wcat,
    (void*)&n_nodes, (void*)&E, (void*)&nX4, (void*)&nW4, (void*)&Mtiles
  };
  hipError_t rc = hipLaunchCooperativeKernel((void*)k_fused, dim3(NB), dim3(NT),
                                             args, 0, stream);
  if (rc != hipSuccess){
    // deterministic fallback: the round-6 six-kernel pipeline
    int E4 = E >> 2;
    int hist_blocks = ((E4+255)>>8) + ((2*nW4+255)>>8);
    int scat_blocks = ((E4+255)>>8) + ((nX4+255)>>8);
    int gemm_blocks = ((Mtiles + 4)/5) * 2;      // 500
    hipLaunchKernelGGL(k_zero,         dim3((n_nodes+255)/256), dim3(256), 0, stream, counts, n_nodes);
    hipLaunchKernelGGL(k_hist_cvtw,    dim3(hist_blocks),       dim3(256), 0, stream,
                       dst, E, counts, Wl, Wr, Wcat, nW4);
    hipLaunchKernelGGL(k_scan,         dim3(1),                 dim3(1024),0, stream,
                       counts, n_nodes, offsets, cursor);
    hipLaunchKernelGGL(k_scatter_cvtx, dim3(scat_blocks),       dim3(256), 0, stream,
                       src, dst, E, cursor, sorted, x, xb, nX4);
    hipLaunchKernelGGL(k_aggr,         dim3((n_nodes+3)/4),     dim3(256), 0, stream,
                       xb, offsets, sorted, aggr, n_nodes);
    hipLaunchKernelGGL(k_gemm,         dim3(gemm_blocks),       dim3(256), 0, stream,
                       aggr, xb, Wcat, br, out, Mtiles);
  }
}

// Round 9
// 185.046 us; speedup vs baseline: 2.3075x; 2.3075x over previous
//
#include <hip/hip_runtime.h>

#define DIM 256
#define KCAT 512
#define LDSP 264   // LDS row stride in bf16 (256 + 8 pad -> 2-way-max bank aliasing)

typedef unsigned short u16;
typedef unsigned int u32;
typedef __bf16 bf16x8 __attribute__((ext_vector_type(8)));
typedef float f32x4 __attribute__((ext_vector_type(4)));

__device__ inline float bf2f(u16 u){ union{u32 i; float f;} v; v.i=((u32)u)<<16; return v.f; }
__device__ inline u16 f2bf(float f){
  union{float f; u32 i;} v; v.f=f;
  u32 i=v.i;
  return (u16)((i + 0x7FFFu + ((i>>16)&1u)) >> 16);  // RNE
}
__device__ inline ushort4 cvt4(float4 v){
  ushort4 r; r.x=f2bf(v.x); r.y=f2bf(v.y); r.z=f2bf(v.z); r.w=f2bf(v.w); return r;
}

// ---- 1: in-degree histogram (int4) + W->bf16 (Wcat) + x->bf16 (xb) ----
// Wcat[col][0:256] = Wl[col][:], Wcat[col][256:512] = Wr[col][:]
__global__ __launch_bounds__(256) void k_hist_cvt(const int* __restrict__ dst, int E,
    int* __restrict__ counts, const float* __restrict__ Wl, const float* __restrict__ Wr,
    const float* __restrict__ x, u16* __restrict__ Wcat, u16* __restrict__ xb,
    int nW4, int nX4){
  int E4 = E >> 2;
  int hb = (E4 + 255) >> 8;
  int wb = (2*nW4 + 255) >> 8;
  int b = blockIdx.x, t = threadIdx.x;
  if (b < hb){
    int e = b*256 + t;
    if(e < E4){
      int4 d = ((const int4*)dst)[e];
      atomicAdd(counts + d.x, 1);
      atomicAdd(counts + d.y, 1);
      atomicAdd(counts + d.z, 1);
      atomicAdd(counts + d.w, 1);
    }
    if (b==0 && t==0){
      for(int e2 = E4*4; e2 < E; e2++) atomicAdd(counts + dst[e2], 1);
    }
  } else if (b < hb + wb){
    int i = (b - hb)*256 + t;
    if (i < 2*nW4){
      int sel = (i >= nW4);
      int ii = sel ? i - nW4 : i;
      float4 v = sel ? ((const float4*)Wr)[ii] : ((const float4*)Wl)[ii];
      int col = ii >> 6, k4 = ii & 63;      // 64 float4 per 256-f32 row
      ((ushort4*)Wcat)[col*128 + sel*64 + k4] = cvt4(v);
    }
  } else {
    int i = (b - hb - wb)*256 + t;
    if (i < nX4) ((ushort4*)xb)[i] = cvt4(((const float4*)x)[i]);
  }
}

// ---- 2: exclusive scan over counts (single block, 20/thread, static regs) ----
__global__ __launch_bounds__(1024) void k_scan(const int* __restrict__ counts, int n,
                                               int* __restrict__ offsets, int* __restrict__ cursor){
  __shared__ int wsum[16];
  int t = threadIdx.x;
  int s0 = t*20;
  int4 c[5];
  int s = 0;
  #pragma unroll
  for(int u=0; u<5; u++){
    int i = s0 + 4*u;
    int4 cv = {0,0,0,0};
    if (i + 3 < n){
      cv = *(const int4*)(counts + i);
    } else {
      if (i   < n) cv.x = counts[i];
      if (i+1 < n) cv.y = counts[i+1];
      if (i+2 < n) cv.z = counts[i+2];
      if (i+3 < n) cv.w = counts[i+3];
    }
    c[u] = cv;
    s += cv.x + cv.y + cv.z + cv.w;
  }
  int lane = t & 63, wid = t >> 6;
  int sc = s;
  #pragma unroll
  for(int off=1; off<64; off<<=1){
    int v = __shfl_up(sc, off, 64);
    if (lane >= off) sc += v;
  }
  if (lane == 63) wsum[wid] = sc;
  __syncthreads();
  if (t == 0){
    int run = 0;
    #pragma unroll
    for(int w=0; w<16; w++){ int v = wsum[w]; wsum[w] = run; run += v; }
  }
  __syncthreads();
  int run = wsum[wid] + (sc - s);
  #pragma unroll
  for(int u=0; u<5; u++){
    int i = s0 + 4*u;
    int4 o;
    o.x = run; run += c[u].x;
    o.y = run; run += c[u].y;
    o.z = run; run += c[u].z;
    o.w = run; run += c[u].w;
    if (i + 3 < n){
      *(int4*)(offsets + i) = o;
      *(int4*)(cursor  + i) = o;
    } else {
      if (i   < n){ offsets[i]   = o.x; cursor[i]   = o.x; }
      if (i+1 < n){ offsets[i+1] = o.y; cursor[i+1] = o.y; }
      if (i+2 < n){ offsets[i+2] = o.z; cursor[i+2] = o.z; }
      if (i+3 < n){ offsets[i+3] = o.w; cursor[i+3] = o.w; }
    }
  }
  if (t == 1023) offsets[n] = wsum[15] + sc;
}

// ---- 3: scatter edge sources into CSR order (int4) ----
__global__ __launch_bounds__(256) void k_scatter(const int* __restrict__ src,
    const int* __restrict__ dst, int E, int* __restrict__ cursor, int* __restrict__ sorted_src){
  int E4 = E >> 2;
  int e = blockIdx.x*256 + threadIdx.x;
  if(e < E4){
    int4 s = ((const int4*)src)[e];
    int4 d = ((const int4*)dst)[e];
    sorted_src[atomicAdd(cursor + d.x, 1)] = s.x;
    sorted_src[atomicAdd(cursor + d.y, 1)] = s.y;
    sorted_src[atomicAdd(cursor + d.z, 1)] = s.z;
    sorted_src[atomicAdd(cursor + d.w, 1)] = s.w;
  }
  if (e == 0){
    for(int e2 = E4*4; e2 < E; e2++)
      sorted_src[atomicAdd(cursor + dst[e2], 1)] = src[e2];
  }
}

// ---- 4: fused aggregate+GEMM. One block per 16-row M-tile (1250 blocks). ----
// Phase a: 4 waves x 4 nodes: mean of gathered xb rows -> LDS (bf16, stride LDSP).
// Phase b: per wave, 2 col-groups of 32 cols: B-frags (128 VGPR) from Wcat,
//          A-frags: aggr-half from LDS, x-half from global xb. 64 MFMAs/group.
// A frag: lane(quad*16+l16) holds A[l16][kt*32+quad*8+j] (16B contiguous)
// D:      lane reg r holds D[quad*4+r][l16]
__global__ __launch_bounds__(256, 2) void k_aggr_gemm(const u16* __restrict__ xb,
    const int* __restrict__ offsets, const int* __restrict__ sorted_src,
    const u16* __restrict__ Wcat, const float* __restrict__ br,
    float* __restrict__ out, int n_nodes){
  __shared__ u16 at[16*LDSP];
  int t = threadIdx.x, wid = t >> 6, lane = t & 63;
  int row0 = blockIdx.x*16;
  if (row0 >= n_nodes) return;

  // ---- phase a: aggregation into LDS ----
  {
    const u16* xc = xb + lane*4;
    #pragma unroll
    for(int u=0; u<4; u++){
      int r = wid*4 + u;
      int node = row0 + r;
      float s0=0.f, s1=0.f, s2=0.f, s3=0.f;
      int deg = 0;
      if (node < n_nodes){
        int b0 = offsets[node], b1 = offsets[node+1];
        deg = b1 - b0;
        int i = b0;
        for(; i+8 <= b1; i+=8){
          int idx[8];
          #pragma unroll
          for(int k=0;k<8;k++) idx[k] = sorted_src[i+k];
          ushort4 vv[8];
          #pragma unroll
          for(int k=0;k<8;k++) vv[k] = *(const ushort4*)(xc + (size_t)idx[k]*DIM);
          #pragma unroll
          for(int k=0;k<8;k++){
            s0 += bf2f(vv[k].x); s1 += bf2f(vv[k].y); s2 += bf2f(vv[k].z); s3 += bf2f(vv[k].w);
          }
        }
        for(; i < b1; i++){
          int sn = sorted_src[i];
          ushort4 vv = *(const ushort4*)(xc + (size_t)sn*DIM);
          s0 += bf2f(vv.x); s1 += bf2f(vv.y); s2 += bf2f(vv.z); s3 += bf2f(vv.w);
        }
      }
      float inv = 1.0f / (float)(deg > 1 ? deg : 1);
      ushort4 o;
      o.x = f2bf(s0*inv); o.y = f2bf(s1*inv); o.z = f2bf(s2*inv); o.w = f2bf(s3*inv);
      *(ushort4*)(&at[r*LDSP + lane*4]) = o;
    }
  }
  __syncthreads();

  // ---- phase b: GEMM 16 rows x 256 cols ----
  int quad = lane >> 4, l16 = lane & 15;

  bf16x8 Aa[8], Ax[8];
  #pragma unroll
  for(int kt=0; kt<8; kt++)
    Aa[kt] = *(const bf16x8*)(&at[l16*LDSP + kt*32 + quad*8]);
  const u16* xrow = xb + (size_t)(row0 + l16)*DIM + quad*8;
  #pragma unroll
  for(int kt=0; kt<8; kt++)
    Ax[kt] = *(const bf16x8*)(xrow + kt*32);

  #pragma unroll 1      // keep only one group's B-frags live (VGPR budget)
  for(int gidx=0; gidx<2; gidx++){
    int colbase = gidx*128 + wid*32;
    const u16* wbase = Wcat + (size_t)(colbase + l16)*KCAT + quad*8;
    bf16x8 B[2][16];
    #pragma unroll
    for(int ct=0; ct<2; ct++)
      #pragma unroll
      for(int kt=0; kt<16; kt++)
        B[ct][kt] = *(const bf16x8*)(wbase + (size_t)ct*16*KCAT + kt*32);

    int col0 = colbase + l16, col1 = col0 + 16;
    float bi0 = br[col0], bi1 = br[col1];

    f32x4 acc0 = {0.f,0.f,0.f,0.f}, acc1 = {0.f,0.f,0.f,0.f};
    #pragma unroll
    for(int kt=0; kt<8; kt++){
      acc0 = __builtin_amdgcn_mfma_f32_16x16x32_bf16(Aa[kt], B[0][kt], acc0, 0, 0, 0);
      acc1 = __builtin_amdgcn_mfma_f32_16x16x32_bf16(Aa[kt], B[1][kt], acc1, 0, 0, 0);
    }
    #pragma unroll
    for(int kt=0; kt<8; kt++){
      acc0 = __builtin_amdgcn_mfma_f32_16x16x32_bf16(Ax[kt], B[0][kt+8], acc0, 0, 0, 0);
      acc1 = __builtin_amdgcn_mfma_f32_16x16x32_bf16(Ax[kt], B[1][kt+8], acc1, 0, 0, 0);
    }
    size_t base = (size_t)(row0 + quad*4)*DIM;
    #pragma unroll
    for(int r=0;r<4;r++){
      out[base + (size_t)r*DIM + col0] = acc0[r] + bi0;
      out[base + (size_t)r*DIM + col1] = acc1[r] + bi1;
    }
  }
}

extern "C" void kernel_launch(void* const* d_in, const int* in_sizes, int n_in,
                              void* d_out, int out_size, void* d_ws, size_t ws_size,
                              hipStream_t stream){
  const float* x  = (const float*)d_in[0];
  const int*   ei = (const int*)d_in[1];
  const float* Wl = (const float*)d_in[2];
  const float* Wr = (const float*)d_in[3];
  const float* br = (const float*)d_in[4];
  float* out = (float*)d_out;
  int n_nodes = in_sizes[0] / DIM;   // 20000
  int E = in_sizes[1] / 2;           // 320000
  const int* src = ei;
  const int* dst = ei + E;

  // workspace layout (16B aligned sections): ~12 MB
  int* counts  = (int*)d_ws;                   // [n]
  int* offsets = counts + n_nodes;             // [n+1] (padded to n+8)
  int* cursor  = offsets + (n_nodes + 8);      // [n]
  int* sorted  = cursor + n_nodes;             // [E]
  u16* xb      = (u16*)(sorted + E);           // [n*DIM] bf16
  u16* Wcat    = xb + (size_t)n_nodes*DIM;     // [256*512] bf16: [Wl | Wr] per col

  int nX4 = n_nodes*DIM/4, nW4 = DIM*DIM/4;
  int E4 = E >> 2;
  int hist_blocks = ((E4+255)>>8) + ((2*nW4+255)>>8) + ((nX4+255)>>8);
  int Mtiles = (n_nodes + 15) >> 4;            // 1250

  hipMemsetAsync(counts, 0, (size_t)n_nodes*sizeof(int), stream);
  hipLaunchKernelGGL(k_hist_cvt,  dim3(hist_blocks),   dim3(256), 0, stream,
                     dst, E, counts, Wl, Wr, x, Wcat, xb, nW4, nX4);
  hipLaunchKernelGGL(k_scan,      dim3(1),             dim3(1024),0, stream,
                     counts, n_nodes, offsets, cursor);
  hipLaunchKernelGGL(k_scatter,   dim3((E4+255)/256),  dim3(256), 0, stream,
                     src, dst, E, cursor, sorted);
  hipLaunchKernelGGL(k_aggr_gemm, dim3(Mtiles),        dim3(256), 0, stream,
                     xb, offsets, sorted, Wcat, br, out, n_nodes);
}